// Round 4
// baseline (24929.846 us; speedup 1.0000x reference)
//
#include <hip/hip_runtime.h>

#define DI __device__ __forceinline__

typedef __bf16  bf16x8 __attribute__((ext_vector_type(8)));
typedef float   f32x4  __attribute__((ext_vector_type(4)));
typedef unsigned short u16;
typedef unsigned int   u32;

DI u16 f2bf(float f){ u32 u = __float_as_uint(f); u32 r = 0x7fffu + ((u>>16)&1u); return (u16)((u + r) >> 16); }
DI float bf2f(u16 h){ return __uint_as_float(((u32)h)<<16); }

union U16x8 { u16 u[8]; uint4 v; };
union AB    { uint4 u; bf16x8 b; };

#define MFMA(a,b,c) __builtin_amdgcn_mfma_f32_16x16x32_bf16((a),(b),(c),0,0,0)

// async global->LDS, 16B/lane, wave-uniform LDS base.
DI void gload16(const void* g, void* l){
  __builtin_amdgcn_global_load_lds((const __attribute__((address_space(1))) u32*)g,
                                   (__attribute__((address_space(3))) u32*)l, 16, 0, 0);
}
// coherent (L3-level) 16B load: bypasses L1+L2 -> sees peer XCD writes.
DI void aload(uint4& d, const void* p){
  asm volatile("global_load_dwordx4 %0, %1, off sc0 sc1" : "=&v"(d) : "v"(p) : "memory");
}
// coherent u16 store: write-through to L3 coherence point.
DI void sstore16(void* p, u16 v){
  asm volatile("global_store_short %0, %1, off sc0 sc1" :: "v"(p), "v"((u32)v) : "memory");
}
template<int N> DI void wait_vmcnt(){ asm volatile("s_waitcnt vmcnt(%0)" :: "n"(N) : "memory"); }
DI void vwait(int n){
  switch(n){
    case 0:  wait_vmcnt<0>();  break;
    case 7:  wait_vmcnt<7>();  break;
    case 8:  wait_vmcnt<8>();  break;
    case 11: wait_vmcnt<11>(); break;
    default: wait_vmcnt<14>(); break;
  }
}
DI void spinf(u32* f){
  while (__hip_atomic_load(f, __ATOMIC_RELAXED, __HIP_MEMORY_SCOPE_AGENT) < 16u)
    __builtin_amdgcn_s_sleep(8);
}

// ---- problem constants
#define Tn 512
#define Bn 2048
#define Fn 16
#define Hn 512
#define NK32 16

// ---- workspace layout (bytes)
#define OFF_WH0   0ull
#define OFF_WI1   3145728ull
#define OFF_WH1   6291456ull
#define OFF_WI0   9437184ull
#define OFF_H0HI  9633792ull
#define OFF_H0LO  13828096ull
#define OFF_H1HI  18022400ull
#define OFF_H1LO  22216704ull
#define OFF_FLAGS 26411008ull
// total 26476544 bytes

// =====================================================================
// Prep: fp32 [3H x K] weights -> frag-linear bf16 hi/lo subtile pairs.
// Subtile (16j x 32k) = 64 lanes x 16B, lane = (j&15) + ((k>>3)&3)*16.
// pair = {hi 1KB, lo 1KB}; pairidx = (g*32 + (j>>4))*nk + k32.
// =====================================================================
__global__ __launch_bounds__(256) void prep_w(const float* __restrict__ w0,
                                              const float* __restrict__ w1,
                                              const float* __restrict__ w2,
                                              u16* __restrict__ dst){
  int tid = blockIdx.x*256 + threadIdx.x;        // 294912 total
  int p = tid / 98304, rem = tid % 98304;        // 0=WH0 1=WI1 2=WH1
  int g = rem / 32768, rem2 = rem % 32768;
  int j = rem2 / 64,   k8 = rem2 % 64;
  const float* src = (p==0) ? w0 : ((p==1) ? w1 : w2);
  const float* s = src + (size_t)(g*Hn + j)*Hn + k8*8;
  U16x8 hi, lo;
#pragma unroll
  for (int i=0;i<8;++i){ float v = s[i]; u16 h = f2bf(v); hi.u[i]=h; lo.u[i]=f2bf(v - bf2f(h)); }
  size_t pairidx = (size_t)(g*32 + (j>>4))*16 + (k8>>2);
  u16* d = dst + (size_t)p*1572864 + pairidx*1024 + (size_t)((j&15) + (k8&3)*16)*8;
  *(uint4*)d = hi.v;
  *(uint4*)(d + 512) = lo.v;
}

__global__ __launch_bounds__(256) void prep_wi0(const float* __restrict__ w,
                                                u16* __restrict__ dst){
  int tid = blockIdx.x*256 + threadIdx.x;        // 6144 total
  int g = tid / 2048, j = (tid % 2048) >> 2, k8 = tid & 3;
  U16x8 hi, lo;
  if (k8 < 2){
    const float* s = w + (size_t)(g*Hn + j)*Fn + k8*8;
#pragma unroll
    for (int i=0;i<8;++i){ float v = s[i]; u16 h = f2bf(v); hi.u[i]=h; lo.u[i]=f2bf(v - bf2f(h)); }
  } else {
#pragma unroll
    for (int i=0;i<8;++i){ hi.u[i]=0; lo.u[i]=0; }
  }
  size_t pairidx = (size_t)(g*32 + (j>>4));
  u16* d = dst + pairidx*1024 + (size_t)((j&15) + k8*16)*8;
  *(uint4*)d = hi.v;
  *(uint4*)(d + 512) = lo.v;
}

// zero parity-1 h buffers (initial state) + flags
__global__ __launch_bounds__(256) void zero_ws(char* __restrict__ ws){
  int tid = blockIdx.x*256 + threadIdx.x;        // 528384 x 16B
  uint4 z = {0u,0u,0u,0u};
  size_t o;
  if      (tid < 131072) o = OFF_H0HI + 2097152 + (size_t)tid*16;
  else if (tid < 262144) o = OFF_H0LO + 2097152 + (size_t)(tid-131072)*16;
  else if (tid < 393216) o = OFF_H1HI + 2097152 + (size_t)(tid-262144)*16;
  else if (tid < 524288) o = OFF_H1LO + 2097152 + (size_t)(tid-393216)*16;
  else                   o = OFF_FLAGS + (size_t)(tid-524288)*16;
  *(uint4*)(ws + o) = z;
}

struct Ctx {
  const u16 *Wi, *Wh;
  const u16 *Ahi_i, *Alo_i, *Ahi_h, *Alo_h;
  u16 *Ohi, *Olo;
  const float* xs;
};

struct PArgs {
  const u16 *Wi0, *Wh0, *Wi1, *Wh1;
  const float *x, *bi0, *bh0, *bi1, *bh1;
  u16 *H0HI, *H0LO, *H1HI, *H1LO;
  u32 *flags;
};

// =====================================================================
// One GRU layer-step inside the persistent kernel.
// Block = 256 thr (4 waves), tile 128 rows x 32 cols; wave = 32r x 32c.
// W -> LDS slots (4 x 12KB, mod-4) via global_load_lds, depth-3.
// A (h hi/lo) -> regs via coherent dwordx4, depth-3. 7 VMEM/set/wave.
// acc[m][cg][0]=r  [1]=z  [2]=i_n  [3]=h_n.
// =====================================================================
template<int LAY>
DI void layer_step(const Ctx& c, char* smem, int tid, int lane, int wv,
                   int mt, int jt,
                   f32x4 (&hprev)[2][2],
                   const float (&SR)[2], const float (&SZ)[2],
                   const float (&BIN)[2], const float (&BHN)[2],
                   u32* sp1, u32* sp2, u32* pub)
{
  constexpr int NI = (LAY==0) ? 1 : 16;
  constexpr int NT = (LAY==0) ? 17 : 32;

  f32x4 acc[2][2][4];
#pragma unroll
  for (int m=0;m<2;++m)
#pragma unroll
    for (int cg=0;cg<2;++cg)
#pragma unroll
      for (int o=0;o<4;++o){ f32x4 z={0.f,0.f,0.f,0.f}; acc[m][cg][o]=z; }

  uint4 areg[16];

  auto issueW = [&](int tt){
    char* buf = smem + (tt & 3)*12288;
    bool ish = tt >= NI;
    const u16* w; int nk, k32;
    if (LAY==0 && !ish){ w = c.Wi; nk = 1; k32 = 0; }
    else if (!ish)     { w = c.Wi; nk = NK32; k32 = tt; }
    else               { w = c.Wh; nk = NK32; k32 = tt - NI; }
#pragma unroll
    for (int ii=0; ii<3; ++ii){
      int task = wv*3 + ii;                       // 0..11 = g*4+cg*2+hl
      int g = task>>2, cg = (task>>1)&1, hl = task&1;
      size_t go = ((size_t)((g*32 + jt*2 + cg)*nk + k32))*1024 + (size_t)hl*512 + (size_t)lane*8;
      gload16(w + go, buf + task*1024);
    }
  };

  auto issueA = [&](int tt){
    uint4* dst = &areg[(tt & 3)*4];
    bool ish = tt >= NI;
    const u16 *ahi, *alo; int k32;
    if (LAY==0 && !ish){ ahi = c.Ahi_h; alo = c.Alo_h; k32 = 0; }   // dummy (uniform count)
    else if (!ish)     { ahi = c.Ahi_i; alo = c.Alo_i; k32 = tt; }
    else               { ahi = c.Ahi_h; alo = c.Alo_h; k32 = tt - NI; }
#pragma unroll
    for (int m=0;m<2;++m){
      size_t go = ((size_t)((mt*8 + wv*2 + m)*NK32 + k32))*512 + (size_t)lane*8;
      aload(dst[m*2],   ahi + go);
      aload(dst[m*2+1], alo + go);
    }
  };

  // ---- L0: stage x tile (K=16 -> padded 32) frag-linear into LDS
  if (LAY==0){
    int row = tid >> 1, half = tid & 1;
    const float* xsrc = c.xs + (size_t)(mt*128 + row)*Fn + half*8;
    U16x8 u;
#pragma unroll
    for (int i=0;i<8;++i) u.u[i] = f2bf(xsrc[i]);
    char* dst = smem + 49152 + (row>>4)*1024 + (size_t)((row&15) + half*16)*16;
    *(uint4*)dst = u.v;
    uint4 z = {0u,0u,0u,0u};
    char* dz = smem + 49152 + (row>>4)*1024 + (size_t)((row&15) + (half+2)*16)*16;
    *(uint4*)dz = z;
  }

  // ---- W prefetch BEFORE spin (hides fill under the wait), A after barrier
  issueW(0); issueW(1); issueW(2);
  if (tid == 0){
    if (sp1) spinf(sp1);
    if (sp2) spinf(sp2);
  }
  asm volatile("s_waitcnt lgkmcnt(0)" ::: "memory");
  __builtin_amdgcn_sched_barrier(0);
  __builtin_amdgcn_s_barrier();
  __builtin_amdgcn_sched_barrier(0);
  issueA(0); issueA(1); issueA(2);

#pragma unroll
  for (int t=0; t<NT; ++t){
    int lvl = (t==0) ? 8 : (t==1) ? 11 : (t==NT-1) ? 0 : (t==NT-2) ? 7 : 14;
    vwait(lvl);
    __builtin_amdgcn_sched_barrier(0);
    __builtin_amdgcn_s_barrier();
    __builtin_amdgcn_sched_barrier(0);
    {
      const char* buf = smem + (t & 3)*12288;
      bool ish = t >= NI;
      bf16x8 a_hi[2], a_lo[2];
      if (!(LAY==0 && t==0)){
        const uint4* ar = &areg[(t & 3)*4];
        AB u0,u1,u2,u3;
        u0.u=ar[0]; u1.u=ar[1]; u2.u=ar[2]; u3.u=ar[3];
        a_hi[0]=u0.b; a_lo[0]=u1.b; a_hi[1]=u2.b; a_lo[1]=u3.b;
      } else {
        a_hi[0] = *(const bf16x8*)(smem + 49152 + (wv*2+0)*1024 + lane*16);
        a_hi[1] = *(const bf16x8*)(smem + 49152 + (wv*2+1)*1024 + lane*16);
      }
#pragma unroll
      for (int g=0; g<3; ++g)
#pragma unroll
        for (int cg=0; cg<2; ++cg){
          bf16x8 whi = *(const bf16x8*)(buf + (g*4+cg*2+0)*1024 + lane*16);
          bf16x8 wlo = *(const bf16x8*)(buf + (g*4+cg*2+1)*1024 + lane*16);
          int gi = (g<2) ? g : (ish ? 3 : 2);
#pragma unroll
          for (int m=0;m<2;++m){
            if (LAY==0 && t==0){
              acc[m][cg][gi] = MFMA(a_hi[m], whi, acc[m][cg][gi]);
              acc[m][cg][gi] = MFMA(a_hi[m], wlo, acc[m][cg][gi]);
            } else {
              acc[m][cg][gi] = MFMA(a_hi[m], whi, acc[m][cg][gi]);
              acc[m][cg][gi] = MFMA(a_hi[m], wlo, acc[m][cg][gi]);
              acc[m][cg][gi] = MFMA(a_lo[m], whi, acc[m][cg][gi]);
            }
          }
        }
    }
    if (t+3 < NT){ issueW(t+3); issueA(t+3); }
  }

  // ---- GRU epilogue; h_prev comes from registers
  const int col = lane & 15, rg = lane >> 4;
#pragma unroll
  for (int m=0;m<2;++m)
#pragma unroll
    for (int cg=0;cg<2;++cg){
      int j = jt*32 + cg*16 + col;
      size_t foj = (size_t)(j>>5)*512 + (size_t)((j>>3)&3)*128 + (size_t)(j&7);
#pragma unroll
      for (int r=0;r<4;++r){
        int b = mt*128 + wv*32 + m*16 + rg*4 + r;
        float pr  = acc[m][cg][0][r] + SR[cg];
        float pz  = acc[m][cg][1][r] + SZ[cg];
        float pin = acc[m][cg][2][r] + BIN[cg];
        float phn = acc[m][cg][3][r] + BHN[cg];
        float rgt = 1.f/(1.f + __expf(-pr));
        float zgt = 1.f/(1.f + __expf(-pz));
        float e2  = __expf(2.f*(pin + rgt*phn));
        float nn  = 1.f - 2.f/(e2 + 1.f);
        float hv  = hprev[m][cg][r];
        float hnv = (1.f - zgt)*nn + zgt*hv;
        hprev[m][cg][r] = hnv;
        u16 hi = f2bf(hnv);
        u16 lo = f2bf(hnv - bf2f(hi));
        size_t fo = (size_t)(b>>4)*NK32*512 + foj + (size_t)(b&15)*8;
        sstore16(c.Ohi + fo, hi);
        sstore16(c.Olo + fo, lo);
      }
    }
  asm volatile("s_waitcnt vmcnt(0)" ::: "memory");
  __builtin_amdgcn_sched_barrier(0);
  __builtin_amdgcn_s_barrier();
  if (tid == 0) atomicAdd(pub, 1u);
}

// =====================================================================
// Persistent kernel: 256 blocks (forced 1/CU via 84KB LDS), all 512 steps.
// bid -> xcd=bid&7, mt=(bid&7)*2+((bid>>3)&1), jt=bid>>4.
// Sync: flags[lay][s][mt], 16 jt-producers each; h-state via L3 (sc0 sc1).
// =====================================================================
__global__ __launch_bounds__(256, 1) void gru_persist(PArgs a){
  __shared__ __align__(16) char smem[86016];   // 4x12KB W + 8KB x + pad (>80KB => 1 block/CU)
  const int tid = threadIdx.x, lane = tid & 63, wv = tid >> 6;
  const int bid = blockIdx.x;
  const int mt = (bid & 7)*2 + ((bid >> 3) & 1);
  const int jt = bid >> 4;
  const int col = lane & 15;

  float SR[2][2], SZ[2][2], BIN[2][2], BHN[2][2];
#pragma unroll
  for (int cg=0; cg<2; ++cg){
    int j = jt*32 + cg*16 + col;
    SR[0][cg]  = a.bi0[j] + a.bh0[j];
    SZ[0][cg]  = a.bi0[Hn+j] + a.bh0[Hn+j];
    BIN[0][cg] = a.bi0[2*Hn+j];
    BHN[0][cg] = a.bh0[2*Hn+j];
    SR[1][cg]  = a.bi1[j] + a.bh1[j];
    SZ[1][cg]  = a.bi1[Hn+j] + a.bh1[Hn+j];
    BIN[1][cg] = a.bi1[2*Hn+j];
    BHN[1][cg] = a.bh1[2*Hn+j];
  }
  f32x4 hp0[2][2], hp1[2][2];
#pragma unroll
  for (int m=0;m<2;++m)
#pragma unroll
    for (int cg=0;cg<2;++cg){ f32x4 z={0.f,0.f,0.f,0.f}; hp0[m][cg]=z; hp1[m][cg]=z; }

#pragma unroll 1
  for (int s=0; s<Tn; ++s){
    int p = s & 1;
    {
      Ctx c;
      c.Wi = a.Wi0; c.Wh = a.Wh0;
      c.Ahi_i = a.H0HI; c.Alo_i = a.H0LO;   // unused (x path)
      c.Ahi_h = a.H0HI + (size_t)(p^1)*1048576;
      c.Alo_h = a.H0LO + (size_t)(p^1)*1048576;
      c.Ohi   = a.H0HI + (size_t)p*1048576;
      c.Olo   = a.H0LO + (size_t)p*1048576;
      c.xs    = a.x + (size_t)s*Bn*Fn;
      u32* w1 = (s>0) ? &a.flags[(size_t)(s-1)*16 + mt] : nullptr;
      layer_step<0>(c, smem, tid, lane, wv, mt, jt, hp0,
                    SR[0], SZ[0], BIN[0], BHN[0],
                    w1, nullptr, &a.flags[(size_t)s*16 + mt]);
    }
    {
      Ctx c;
      c.Wi = a.Wi1; c.Wh = a.Wh1;
      c.Ahi_i = a.H0HI + (size_t)p*1048576;
      c.Alo_i = a.H0LO + (size_t)p*1048576;
      c.Ahi_h = a.H1HI + (size_t)(p^1)*1048576;
      c.Alo_h = a.H1LO + (size_t)(p^1)*1048576;
      c.Ohi   = a.H1HI + (size_t)p*1048576;
      c.Olo   = a.H1LO + (size_t)p*1048576;
      c.xs    = nullptr;
      u32* w1 = &a.flags[(size_t)s*16 + mt];
      u32* w2 = (s>0) ? &a.flags[(size_t)(512 + s - 1)*16 + mt] : nullptr;
      layer_step<1>(c, smem, tid, lane, wv, mt, jt, hp1,
                    SR[1], SZ[1], BIN[1], BHN[1],
                    w1, w2, &a.flags[(size_t)(512 + s)*16 + mt]);
    }
  }
}

// final projection: out[b][o] = h1[b,:] . Wout[o,:] + bout[o]
__global__ __launch_bounds__(64) void outproj(const u16* __restrict__ h1hi,
                                              const u16* __restrict__ h1lo,
                                              const float* __restrict__ Wout,
                                              const float* __restrict__ bout,
                                              float* __restrict__ out){
  int b = blockIdx.x, l = threadIdx.x;
  float a[8] = {0.f,0.f,0.f,0.f,0.f,0.f,0.f,0.f};
  for (int jj = l; jj < Hn; jj += 64){
    size_t fo = ((size_t)(b>>4)*NK32 + (jj>>5))*512 + (size_t)((b&15) + ((jj>>3)&3)*16)*8 + (jj&7);
    float hv = bf2f(h1hi[fo]) + bf2f(h1lo[fo]);
#pragma unroll
    for (int o=0;o<8;++o) a[o] += hv * Wout[o*Hn + jj];
  }
#pragma unroll
  for (int o=0;o<8;++o){
#pragma unroll
    for (int off=32; off; off>>=1) a[o] += __shfl_xor(a[o], off);
  }
  if (l == 0){
#pragma unroll
    for (int o=0;o<8;++o) out[b*8+o] = a[o] + bout[o];
  }
}

extern "C" void kernel_launch(void* const* d_in, const int* in_sizes, int n_in,
                              void* d_out, int out_size, void* d_ws, size_t ws_size,
                              hipStream_t stream){
  (void)in_sizes; (void)n_in; (void)out_size; (void)ws_size;
  const float* x    = (const float*)d_in[0];
  const float* Wih0 = (const float*)d_in[1];
  const float* Whh0 = (const float*)d_in[2];
  const float* bih0 = (const float*)d_in[3];
  const float* bhh0 = (const float*)d_in[4];
  const float* Wih1 = (const float*)d_in[5];
  const float* Whh1 = (const float*)d_in[6];
  const float* bih1 = (const float*)d_in[7];
  const float* bhh1 = (const float*)d_in[8];
  const float* Wout = (const float*)d_in[9];
  const float* bout = (const float*)d_in[10];
  char* ws = (char*)d_ws;

  prep_w  <<<1152, 256, 0, stream>>>(Whh0, Wih1, Whh1, (u16*)(ws + OFF_WH0));
  prep_wi0<<<  24, 256, 0, stream>>>(Wih0, (u16*)(ws + OFF_WI0));
  zero_ws <<<2064, 256, 0, stream>>>(ws);

  PArgs pa;
  pa.Wi0 = (const u16*)(ws + OFF_WI0);
  pa.Wh0 = (const u16*)(ws + OFF_WH0);
  pa.Wi1 = (const u16*)(ws + OFF_WI1);
  pa.Wh1 = (const u16*)(ws + OFF_WH1);
  pa.x = x; pa.bi0 = bih0; pa.bh0 = bhh0; pa.bi1 = bih1; pa.bh1 = bhh1;
  pa.H0HI = (u16*)(ws + OFF_H0HI); pa.H0LO = (u16*)(ws + OFF_H0LO);
  pa.H1HI = (u16*)(ws + OFF_H1HI); pa.H1LO = (u16*)(ws + OFF_H1LO);
  pa.flags = (u32*)(ws + OFF_FLAGS);

  gru_persist<<<256, 256, 0, stream>>>(pa);

  outproj<<<2048, 64, 0, stream>>>(
      (const u16*)(ws + OFF_H1HI) + 1048576,
      (const u16*)(ws + OFF_H1LO) + 1048576,
      Wout, bout, (float*)d_out);
}